// Round 18
// baseline (161.067 us; speedup 1.0000x reference)
//
#include <hip/hip_runtime.h>
#include <stdint.h>

#define N1 8192
#define N2 8192
#define DK 128
#define TAU 0.08f     // repair margin (sim units); ~15 sigma of f16 dot noise
#define BIAS 256.0f   // sim in [-70,70] -> biased keys are positive floats
#define LDR 132       // staging LDS row stride in f16 (264 B)

typedef _Float16 half8 __attribute__((ext_vector_type(8)));
typedef _Float16 half4 __attribute__((ext_vector_type(4)));
typedef float floatx4 __attribute__((ext_vector_type(4)));

// Module-scope device scratch (graph-capture safe). Fully rewritten each launch.
__device__ __align__(16) _Float16 g_Af[N1 * DK];        // 2 MB
__device__ __align__(16) _Float16 g_Bf[N2 * DK];        // 2 MB
__device__ __align__(16) float2 g_rowtop2[64 * N1];     // 4 MB [128colgrp][row] tile-owned
__device__ __align__(16) float2 g_coltop2[64 * N2];     // 4 MB [128rowgrp][col]
__device__ int g_nn21[N2];

// ---- biased-float keys (group top2; quant <= 3.9e-3 << TAU) ----
__device__ __forceinline__ float bkey(float v, unsigned idx) {
    unsigned b = __float_as_uint(v + BIAS);
    return __uint_as_float((b & 0xFFFFFF80u) | idx);
}
__device__ __forceinline__ float bval(float key) {
    return __uint_as_float(__float_as_uint(key) & 0xFFFFFF80u);
}
__device__ __forceinline__ int bidx(float key) {
    return (int)(__float_as_uint(key) & 127u);
}
__device__ __forceinline__ void push2f(float& t1, float& t2, float p) {
    float m = __builtin_amdgcn_fmed3f(t1, t2, p);
    t1 = fmaxf(t1, p);
    t2 = m;
}
__device__ __forceinline__ void merge2f(float& t1, float& t2, float o1, float o2) {
    float x = fmaxf(t2, o2);
    float m = __builtin_amdgcn_fmed3f(t1, o1, x);
    t1 = fmaxf(t1, o1);
    t2 = m;
}
// ---- exact monotone pack for the repair path ----
__device__ __forceinline__ unsigned mono32(float v) {
    unsigned u = __float_as_uint(v);
    return u ^ ((u & 0x80000000u) ? 0xFFFFFFFFu : 0x80000000u);
}
__device__ __forceinline__ float unmono32(unsigned k) {
    unsigned u = (k & 0x80000000u) ? (k ^ 0x80000000u) : ~k;
    return __uint_as_float(u);
}
__device__ __forceinline__ unsigned long long pack64(float d, unsigned idx) {
    return ((unsigned long long)mono32(d) << 32) | (unsigned)(~idx);
}

// fp32 -> f16 staging (R15: direct fp32 fragment loads doubled sim time).
__global__ __launch_bounds__(256) void convert_kernel(const float* __restrict__ A,
                                                      const float* __restrict__ B) {
    int t = blockIdx.x * blockDim.x + threadIdx.x;
    const int perMat = N1 * (DK / 4);
    int which = (t >= perMat) ? 1 : 0;
    const float* src = which ? B : A;
    _Float16* dst = which ? g_Bf : g_Af;
    int i = which ? t - perMat : t;
    int m = i >> 5;
    int kq = i & 31;
    float4 v = *reinterpret_cast<const float4*>(src + (size_t)m * DK + kq * 4);
    half4 h = {(_Float16)v.x, (_Float16)v.y, (_Float16)v.z, (_Float16)v.w};
    *reinterpret_cast<half4*>(dst + (size_t)m * DK + kq * 4) = h;
}

// 128x128 tile per block, 4 waves, LDS-staged fragments (single barrier).
// R17 lesson: sim pinned at ~76us across ALL fragment paths -> the invariant
// is the epilogue's shuffle butterflies (128 dependent ds_bpermute/wave,
// ~60cyc each, chains of 4). This version replaces them with an LDS-transpose
// epilogue: in-register folds, b128 LDS writes, linear independent LDS reads.
__global__ __launch_bounds__(256) void simf16_kernel() {
    // union: staging tiles (67584 B) aliased by epilogue tiles (41600 B)
    __shared__ __align__(16) unsigned char smem[128 * LDR * 2 * 2];
    _Float16* As = reinterpret_cast<_Float16*>(smem);
    _Float16* Bs = As + 128 * LDR;
    float2* rowt = reinterpret_cast<float2*>(smem);            // [32 frp][130] 33280 B
    float2* colt = reinterpret_cast<float2*>(smem + 33280);    // [8 slot][130]  8320 B

    const int tid  = threadIdx.x;
    const int lane = tid & 63;
    const int wave = tid >> 6;
    const int wm = wave >> 1, wn = wave & 1;
    const int fr = lane & 15, q = lane >> 4;

    // XCD swizzle: dispatch-neighbors share ty, clustered tx -> L2 panel reuse.
    const int flat = blockIdx.y * 64 + blockIdx.x;
    const int xcd = flat & 7;
    const int j = flat >> 3;
    const int ty = j >> 3;
    const int tx = ((j & 7) << 3) | xcd;
    const int row0 = ty * 128, col0 = tx * 128;

    // ---- stage A,B tiles (2048 16-B chunks each; fully coalesced) ----
#pragma unroll
    for (int i = 0; i < 8; ++i) {
        int f = i * 256 + tid;
        int r = f >> 4, c = f & 15;
        *reinterpret_cast<float4*>(&As[r * LDR + c * 8]) =
            *reinterpret_cast<const float4*>(g_Af + (size_t)(row0 + r) * DK + c * 8);
        *reinterpret_cast<float4*>(&Bs[r * LDR + c * 8]) =
            *reinterpret_cast<const float4*>(g_Bf + (size_t)(col0 + r) * DK + c * 8);
    }
    __syncthreads();

    floatx4 acc[4][4];
#pragma unroll
    for (int mt = 0; mt < 4; ++mt)
#pragma unroll
        for (int nt = 0; nt < 4; ++nt)
            acc[mt][nt] = (floatx4){0.f, 0.f, 0.f, 0.f};

#pragma unroll
    for (int ks = 0; ks < 4; ++ks) {
        half8 af[4], bf[4];
#pragma unroll
        for (int mt = 0; mt < 4; ++mt)
            af[mt] = *reinterpret_cast<const half8*>(&As[(wm * 64 + mt * 16 + fr) * LDR + ks * 32 + q * 8]);
#pragma unroll
        for (int nt = 0; nt < 4; ++nt)
            bf[nt] = *reinterpret_cast<const half8*>(&Bs[(wn * 64 + nt * 16 + fr) * LDR + ks * 32 + q * 8]);
#pragma unroll
        for (int mt = 0; mt < 4; ++mt)
#pragma unroll
            for (int nt = 0; nt < 4; ++nt)
                acc[mt][nt] = __builtin_amdgcn_mfma_f32_16x16x32_f16(af[mt], bf[nt], acc[mt][nt], 0, 0, 0);
    }
    __syncthreads();   // all waves done reading As/Bs; epi tiles may overwrite

    // ---- epilogue fold+transpose (C/D: col=lane&15, row=q*4+reg) ----
    // row phase: fold 4 nt in-register, write (t1,t2) pairs for reg,reg+1 as b128
#pragma unroll
    for (int mt = 0; mt < 4; ++mt) {
#pragma unroll
        for (int rp = 0; rp < 2; ++rp) {
            const int reg0 = rp * 2, reg1 = reg0 + 1;
            float a1 = 0.f, a2 = 0.f, b1 = 0.f, b2 = 0.f;
#pragma unroll
            for (int nt = 0; nt < 4; ++nt) {
                unsigned cidx = (unsigned)(wn * 64 + nt * 16 + fr);
                push2f(a1, a2, bkey(acc[mt][nt][reg0], cidx));
                push2f(b1, b2, bkey(acc[mt][nt][reg1], cidx));
            }
            int row = wm * 64 + mt * 16 + q * 4 + reg0;   // even
            int frp = wn * 16 + fr;
            *reinterpret_cast<float4*>(&rowt[frp * 130 + row]) =
                make_float4(a1, a2, b1, b2);
        }
    }
    // col phase: fold 16 (mt,reg) in-register, one float2 per nt
#pragma unroll
    for (int nt = 0; nt < 4; ++nt) {
        float t1 = 0.f, t2 = 0.f;
#pragma unroll
        for (int mt = 0; mt < 4; ++mt)
#pragma unroll
            for (int reg = 0; reg < 4; ++reg)
                push2f(t1, t2, bkey(acc[mt][nt][reg], (unsigned)(wm * 64 + mt * 16 + q * 4 + reg)));
        int col = wn * 64 + nt * 16 + fr;
        colt[(wm * 4 + q) * 130 + col] = make_float2(t1, t2);
    }
    __syncthreads();

    // ---- scans: linear independent LDS reads, no shuffle chains ----
    {   // rows: 2 threads/row x 16 entries
        int row = tid >> 1, half = tid & 1;
        float t1 = 0.f, t2 = 0.f;
#pragma unroll
        for (int s = 0; s < 16; ++s) {
            float2 e = rowt[(half * 16 + s) * 130 + row];
            merge2f(t1, t2, e.x, e.y);
        }
        float o1 = __shfl_xor(t1, 1, 64), o2 = __shfl_xor(t2, 1, 64);
        merge2f(t1, t2, o1, o2);
        if (half == 0) g_rowtop2[(size_t)tx * N1 + row0 + row] = make_float2(t1, t2);
    }
    {   // cols: 2 threads/col x 4 entries
        int col = tid >> 1, half = tid & 1;
        float t1 = 0.f, t2 = 0.f;
#pragma unroll
        for (int s = 0; s < 4; ++s) {
            float2 e = colt[(half * 4 + s) * 130 + col];
            merge2f(t1, t2, e.x, e.y);
        }
        float o1 = __shfl_xor(t1, 1, 64), o2 = __shfl_xor(t2, 1, 64);
        merge2f(t1, t2, o1, o2);
        if (half == 0) g_coltop2[(size_t)ty * N2 + col0 + col] = make_float2(t1, t2);
    }
}

// 16 cols per block (512 blocks). Candidates within TAU of approx max get the
// fp32 SEQUENTIAL k-ascending fmaf chain (bitwise reference rounding, R6-proven).
__global__ __launch_bounds__(256) void colfix_kernel(const float* __restrict__ A,
                                                     const float* __restrict__ B) {
    __shared__ float2 tile[64 * 16];          // 8 KB
    __shared__ unsigned long long slot[16];
    __shared__ int cand[256];
    __shared__ int cand_cnt;

    const int tid = threadIdx.x;
    const int c0 = blockIdx.x * 16;

#pragma unroll
    for (int i = 0; i < 4; ++i) {
        int idx = i * 256 + tid;              // 0..1023
        int grp = idx >> 4, c = idx & 15;
        tile[grp * 16 + c] = g_coltop2[(size_t)grp * N2 + c0 + c];
    }
    if (tid < 16) slot[tid] = 0ULL;
    if (tid == 0) cand_cnt = 0;
    __syncthreads();

    const int c = tid >> 4, j = tid & 15;     // 16 threads per col, 4 grps each
    float mx = 0.f;                           // biased domain, all keys > 0
#pragma unroll
    for (int s = 0; s < 4; ++s)
        mx = fmaxf(mx, tile[(j * 4 + s) * 16 + c].x);
    mx = fmaxf(mx, __shfl_xor(mx, 1, 64));
    mx = fmaxf(mx, __shfl_xor(mx, 2, 64));
    mx = fmaxf(mx, __shfl_xor(mx, 4, 64));
    mx = fmaxf(mx, __shfl_xor(mx, 8, 64));
    const float thr = bval(mx) - TAU;
#pragma unroll
    for (int s = 0; s < 4; ++s) {
        int grp = j * 4 + s;
        float2 e = tile[grp * 16 + c];
        if (bval(e.x) >= thr) {
            int rr = grp * 128 + bidx(e.x);
            int si = atomicAdd(&cand_cnt, 1);
            if (si < 256) cand[si] = (c << 16) | rr;
        }
        if (bval(e.y) >= thr) {
            int rr = grp * 128 + bidx(e.y);
            int si = atomicAdd(&cand_cnt, 1);
            if (si < 256) cand[si] = (c << 16) | rr;
        }
    }
    __syncthreads();

    const int nc = min(cand_cnt, 256);
    for (int i = tid; i < nc; i += 256) {
        int pc = cand[i];
        int cl = pc >> 16, rr = pc & 0xFFFF;
        const float* ar = A + (size_t)rr * DK;
        const float* br = B + (size_t)(c0 + cl) * DK;
        float d = 0.0f;
#pragma unroll
        for (int k4 = 0; k4 < DK / 4; ++k4) {
            float4 a = *reinterpret_cast<const float4*>(ar + k4 * 4);
            float4 b = *reinterpret_cast<const float4*>(br + k4 * 4);
            d = fmaf(a.x, b.x, d);
            d = fmaf(a.y, b.y, d);
            d = fmaf(a.z, b.z, d);
            d = fmaf(a.w, b.w, d);
        }
        atomicMax(&slot[cl], pack64(d, (unsigned)rr));
    }
    __syncthreads();

    if (tid < 16) g_nn21[c0 + tid] = (int)(~(unsigned)slot[tid]);
}

// 16 rows per block (512 blocks). Same repair; fuses mutual check and writes
// both outputs (g_nn21 complete from prior colfix launch).
__global__ __launch_bounds__(256) void rowfix_mutual_kernel(const float* __restrict__ A,
                                                            const float* __restrict__ B,
                                                            float* __restrict__ out) {
    __shared__ float2 tile[64 * 16];
    __shared__ unsigned long long slot[16];
    __shared__ int cand[256];
    __shared__ int cand_cnt;

    const int tid = threadIdx.x;
    const int r0 = blockIdx.x * 16;

#pragma unroll
    for (int i = 0; i < 4; ++i) {
        int idx = i * 256 + tid;
        int grp = idx >> 4, r = idx & 15;
        tile[grp * 16 + r] = g_rowtop2[(size_t)grp * N1 + r0 + r];
    }
    if (tid < 16) slot[tid] = 0ULL;
    if (tid == 0) cand_cnt = 0;
    __syncthreads();

    const int r = tid >> 4, j = tid & 15;
    float mx = 0.f;
#pragma unroll
    for (int s = 0; s < 4; ++s)
        mx = fmaxf(mx, tile[(j * 4 + s) * 16 + r].x);
    mx = fmaxf(mx, __shfl_xor(mx, 1, 64));
    mx = fmaxf(mx, __shfl_xor(mx, 2, 64));
    mx = fmaxf(mx, __shfl_xor(mx, 4, 64));
    mx = fmaxf(mx, __shfl_xor(mx, 8, 64));
    const float thr = bval(mx) - TAU;
#pragma unroll
    for (int s = 0; s < 4; ++s) {
        int grp = j * 4 + s;
        float2 e = tile[grp * 16 + r];
        if (bval(e.x) >= thr) {
            int cc = grp * 128 + bidx(e.x);
            int si = atomicAdd(&cand_cnt, 1);
            if (si < 256) cand[si] = (r << 16) | cc;
        }
        if (bval(e.y) >= thr) {
            int cc = grp * 128 + bidx(e.y);
            int si = atomicAdd(&cand_cnt, 1);
            if (si < 256) cand[si] = (r << 16) | cc;
        }
    }
    __syncthreads();

    const int nc = min(cand_cnt, 256);
    for (int i = tid; i < nc; i += 256) {
        int pc = cand[i];
        int rl = pc >> 16, cc = pc & 0xFFFF;
        const float* ar = A + (size_t)(r0 + rl) * DK;
        const float* br = B + (size_t)cc * DK;
        float d = 0.0f;
#pragma unroll
        for (int k4 = 0; k4 < DK / 4; ++k4) {
            float4 a = *reinterpret_cast<const float4*>(ar + k4 * 4);
            float4 b = *reinterpret_cast<const float4*>(br + k4 * 4);
            d = fmaf(a.x, b.x, d);
            d = fmaf(a.y, b.y, d);
            d = fmaf(a.z, b.z, d);
            d = fmaf(a.w, b.w, d);
        }
        atomicMax(&slot[rl], pack64(d, (unsigned)cc));
    }
    __syncthreads();

    if (tid < 16) {
        unsigned long long p = slot[tid];
        int row = r0 + tid;
        int m = (int)(~(unsigned)p);
        out[row] = (float)((g_nn21[m] == row) ? m : -1);     // matches0
        out[N1 + row] = unmono32((unsigned)(p >> 32));       // exact score
    }
}

extern "C" void kernel_launch(void* const* d_in, const int* in_sizes, int n_in,
                              void* d_out, int out_size, void* d_ws, size_t ws_size,
                              hipStream_t stream) {
    const float* A = (const float*)d_in[0];   // desc1 [8192,128] f32
    const float* B = (const float*)d_in[1];   // desc2 [8192,128] f32
    float* out = (float*)d_out;               // [0:8192]=matches, [8192:16384]=scores

    convert_kernel<<<2 * N1 * (DK / 4) / 256, 256, 0, stream>>>(A, B);
    dim3 grid(64, 64);
    simf16_kernel<<<grid, 256, 0, stream>>>();
    colfix_kernel<<<N2 / 16, 256, 0, stream>>>(A, B);
    rowfix_mutual_kernel<<<N1 / 16, 256, 0, stream>>>(A, B, out);
}

// Round 19
// 136.607 us; speedup vs baseline: 1.1791x; 1.1791x over previous
//
#include <hip/hip_runtime.h>
#include <stdint.h>

#define N1 8192
#define N2 8192
#define DK 128
#define TAU 0.08f     // repair margin (sim units); ~15 sigma of f16 dot noise
#define BIAS 256.0f   // sim in [-70,70] -> biased keys are positive floats
#define LDR 132       // staging LDS row stride in f16 (264 B)

typedef _Float16 half8 __attribute__((ext_vector_type(8)));
typedef __fp16 fp16x2 __attribute__((ext_vector_type(2)));
typedef float floatx4 __attribute__((ext_vector_type(4)));

// Module-scope device scratch (graph-capture safe). Fully rewritten each launch.
__device__ __align__(16) float2 g_rowtop2[64 * N1];     // 4 MB [128colgrp][row] tile-owned
__device__ __align__(16) float2 g_coltop2[64 * N2];     // 4 MB [128rowgrp][col]
__device__ int g_nn12[N1];
__device__ int g_nn21[N2];

// ---- biased-float keys (group top2; quant <= 3.9e-3 << TAU) ----
__device__ __forceinline__ float bkey(float v, unsigned idx) {
    unsigned b = __float_as_uint(v + BIAS);
    return __uint_as_float((b & 0xFFFFFF80u) | idx);
}
__device__ __forceinline__ float bval(float key) {
    return __uint_as_float(__float_as_uint(key) & 0xFFFFFF80u);
}
__device__ __forceinline__ int bidx(float key) {
    return (int)(__float_as_uint(key) & 127u);
}
__device__ __forceinline__ void push2f(float& t1, float& t2, float p) {
    float m = __builtin_amdgcn_fmed3f(t1, t2, p);
    t1 = fmaxf(t1, p);
    t2 = m;
}
__device__ __forceinline__ void merge2f(float& t1, float& t2, float o1, float o2) {
    float x = fmaxf(t2, o2);
    float m = __builtin_amdgcn_fmed3f(t1, o1, x);
    t1 = fmaxf(t1, o1);
    t2 = m;
}
// ---- exact monotone pack for the repair path ----
__device__ __forceinline__ unsigned mono32(float v) {
    unsigned u = __float_as_uint(v);
    return u ^ ((u & 0x80000000u) ? 0xFFFFFFFFu : 0x80000000u);
}
__device__ __forceinline__ float unmono32(unsigned k) {
    unsigned u = (k & 0x80000000u) ? (k ^ 0x80000000u) : ~k;
    return __uint_as_float(u);
}
__device__ __forceinline__ unsigned long long pack64(float d, unsigned idx) {
    return ((unsigned long long)mono32(d) << 32) | (unsigned)(~idx);
}
// 8x f32 -> f16 via v_cvt_pkrtz (RTZ; approx GEMM feeds candidate selection
// only, repair is exact fp32 -> rounding mode irrelevant at TAU margin).
__device__ __forceinline__ half8 cvt8(float4 lo, float4 hi) {
    fp16x2 p0 = __builtin_amdgcn_cvt_pkrtz(lo.x, lo.y);
    fp16x2 p1 = __builtin_amdgcn_cvt_pkrtz(lo.z, lo.w);
    fp16x2 p2 = __builtin_amdgcn_cvt_pkrtz(hi.x, hi.y);
    fp16x2 p3 = __builtin_amdgcn_cvt_pkrtz(hi.z, hi.w);
    union { fp16x2 h2[4]; half8 h8; } u;
    u.h2[0] = p0; u.h2[1] = p1; u.h2[2] = p2; u.h2[3] = p3;
    return u.h8;
}

// 128x128 tile per block, 4 waves. Staging fused with fp32->f16 convert:
// coalesced float4 stream loads + in-register cvt + f16 LDS tiles (single
// barrier), then K-loop runs from LDS. Kills the separate convert kernel.
// (R15's fp32 regression was latency-serialized K-loop gathers, not streams.)
// Epilogue: R16/R17 shuffle top2 with biased-float keys (measured-equal best).
__global__ __launch_bounds__(256) void simf16_kernel(const float* __restrict__ A,
                                                     const float* __restrict__ B) {
    __shared__ _Float16 As[128 * LDR];   // 33792 B
    __shared__ _Float16 Bs[128 * LDR];   // 33792 B
    __shared__ float2 lmerge[2][128];    // 2 KB

    const int tid  = threadIdx.x;
    const int lane = tid & 63;
    const int wave = tid >> 6;
    const int wm = wave >> 1, wn = wave & 1;
    const int fr = lane & 15, q = lane >> 4;

    // XCD swizzle: dispatch-neighbors share ty, clustered tx -> L2 panel reuse.
    const int flat = blockIdx.y * 64 + blockIdx.x;
    const int xcd = flat & 7;
    const int j = flat >> 3;
    const int ty = j >> 3;
    const int tx = ((j & 7) << 3) | xcd;
    const int row0 = ty * 128, col0 = tx * 128;

    // ---- stage A,B tiles from fp32 with fused convert (coalesced streams) ----
#pragma unroll
    for (int i = 0; i < 8; ++i) {
        int f = i * 256 + tid;           // chunk 0..2047
        int r = f >> 4, c = f & 15;      // row 0..127, 8-float chunk 0..15
        const float* pa = A + (size_t)(row0 + r) * DK + c * 8;
        const float* pb = B + (size_t)(col0 + r) * DK + c * 8;
        *reinterpret_cast<half8*>(&As[r * LDR + c * 8]) =
            cvt8(*reinterpret_cast<const float4*>(pa),
                 *reinterpret_cast<const float4*>(pa + 4));
        *reinterpret_cast<half8*>(&Bs[r * LDR + c * 8]) =
            cvt8(*reinterpret_cast<const float4*>(pb),
                 *reinterpret_cast<const float4*>(pb + 4));
    }
    __syncthreads();

    floatx4 acc[4][4];
#pragma unroll
    for (int mt = 0; mt < 4; ++mt)
#pragma unroll
        for (int nt = 0; nt < 4; ++nt)
            acc[mt][nt] = (floatx4){0.f, 0.f, 0.f, 0.f};

#pragma unroll
    for (int ks = 0; ks < 4; ++ks) {
        half8 af[4], bf[4];
#pragma unroll
        for (int mt = 0; mt < 4; ++mt)
            af[mt] = *reinterpret_cast<const half8*>(&As[(wm * 64 + mt * 16 + fr) * LDR + ks * 32 + q * 8]);
#pragma unroll
        for (int nt = 0; nt < 4; ++nt)
            bf[nt] = *reinterpret_cast<const half8*>(&Bs[(wn * 64 + nt * 16 + fr) * LDR + ks * 32 + q * 8]);
#pragma unroll
        for (int mt = 0; mt < 4; ++mt)
#pragma unroll
            for (int nt = 0; nt < 4; ++nt)
                acc[mt][nt] = __builtin_amdgcn_mfma_f32_16x16x32_f16(af[mt], bf[nt], acc[mt][nt], 0, 0, 0);
    }

    // ---- row phase: top2 over 128 cols (C/D: col=lane&15, row=q*4+reg) ----
#pragma unroll
    for (int mt = 0; mt < 4; ++mt) {
#pragma unroll
        for (int reg = 0; reg < 4; ++reg) {
            float t1 = 0.f, t2 = 0.f;
#pragma unroll
            for (int nt = 0; nt < 4; ++nt)
                push2f(t1, t2, bkey(acc[mt][nt][reg], (unsigned)(wn * 64 + nt * 16 + fr)));
#pragma unroll
            for (int off = 1; off < 16; off <<= 1) {
                float o1 = __shfl_xor(t1, off, 64);
                float o2 = __shfl_xor(t2, off, 64);
                merge2f(t1, t2, o1, o2);
            }
            if (fr == 0) lmerge[wn][wm * 64 + mt * 16 + q * 4 + reg] = make_float2(t1, t2);
        }
    }
    __syncthreads();
    if (tid < 128) {
        float2 a = lmerge[0][tid], b = lmerge[1][tid];
        merge2f(a.x, a.y, b.x, b.y);
        g_rowtop2[(size_t)tx * N1 + row0 + tid] = a;   // contiguous 1 KB run
    }
    __syncthreads();

    // ---- col phase: top2 over 128 rows ----
#pragma unroll
    for (int nt = 0; nt < 4; ++nt) {
        float t1 = 0.f, t2 = 0.f;
#pragma unroll
        for (int mt = 0; mt < 4; ++mt)
#pragma unroll
            for (int reg = 0; reg < 4; ++reg)
                push2f(t1, t2, bkey(acc[mt][nt][reg], (unsigned)(wm * 64 + mt * 16 + q * 4 + reg)));
        float o1 = __shfl_xor(t1, 16, 64), o2 = __shfl_xor(t2, 16, 64);
        merge2f(t1, t2, o1, o2);
        o1 = __shfl_xor(t1, 32, 64); o2 = __shfl_xor(t2, 32, 64);
        merge2f(t1, t2, o1, o2);
        if (q == 0) lmerge[wm][wn * 64 + nt * 16 + fr] = make_float2(t1, t2);
    }
    __syncthreads();
    if (tid < 128) {
        float2 a = lmerge[0][tid], b = lmerge[1][tid];
        merge2f(a.x, a.y, b.x, b.y);
        g_coltop2[(size_t)ty * N2 + col0 + tid] = a;
    }
}

// 1024 blocks: 0..511 repair cols (g_nn21), 512..1023 repair rows (g_nn12 +
// exact scores). Independent halves -> run concurrently in one launch.
// Candidates within TAU of approx max get the fp32 SEQUENTIAL k-ascending
// fmaf chain (bitwise reference rounding, R6-proven).
__global__ __launch_bounds__(256) void fix_kernel(const float* __restrict__ A,
                                                  const float* __restrict__ B,
                                                  float* __restrict__ out) {
    __shared__ float2 tile[64 * 16];          // 8 KB
    __shared__ unsigned long long slot[16];
    __shared__ int cand[256];
    __shared__ int cand_cnt;

    const int tid = threadIdx.x;
    const bool rowside = blockIdx.x >= 512;
    const int base0 = (blockIdx.x & 511) * 16;
    const float2* top2 = rowside ? g_rowtop2 : g_coltop2;

#pragma unroll
    for (int i = 0; i < 4; ++i) {
        int idx = i * 256 + tid;              // 0..1023
        int grp = idx >> 4, c = idx & 15;
        tile[grp * 16 + c] = top2[(size_t)grp * N1 + base0 + c];
    }
    if (tid < 16) slot[tid] = 0ULL;
    if (tid == 0) cand_cnt = 0;
    __syncthreads();

    const int c = tid >> 4, j = tid & 15;     // 16 threads per row/col
    float mx = 0.f;                           // biased domain, all keys > 0
#pragma unroll
    for (int s = 0; s < 4; ++s)
        mx = fmaxf(mx, tile[(j * 4 + s) * 16 + c].x);
    mx = fmaxf(mx, __shfl_xor(mx, 1, 64));
    mx = fmaxf(mx, __shfl_xor(mx, 2, 64));
    mx = fmaxf(mx, __shfl_xor(mx, 4, 64));
    mx = fmaxf(mx, __shfl_xor(mx, 8, 64));
    const float thr = bval(mx) - TAU;
#pragma unroll
    for (int s = 0; s < 4; ++s) {
        int grp = j * 4 + s;
        float2 e = tile[grp * 16 + c];
        if (bval(e.x) >= thr) {
            int o = grp * 128 + bidx(e.x);
            int si = atomicAdd(&cand_cnt, 1);
            if (si < 256) cand[si] = (c << 16) | o;
        }
        if (bval(e.y) >= thr) {
            int o = grp * 128 + bidx(e.y);
            int si = atomicAdd(&cand_cnt, 1);
            if (si < 256) cand[si] = (c << 16) | o;
        }
    }
    __syncthreads();

    const int nc = min(cand_cnt, 256);
    for (int i = tid; i < nc; i += 256) {
        int pc = cand[i];
        int cl = pc >> 16, other = pc & 0xFFFF;
        const float* ar = rowside ? (A + (size_t)(base0 + cl) * DK) : (A + (size_t)other * DK);
        const float* br = rowside ? (B + (size_t)other * DK) : (B + (size_t)(base0 + cl) * DK);
        float d = 0.0f;
#pragma unroll
        for (int k4 = 0; k4 < DK / 4; ++k4) {
            float4 a = *reinterpret_cast<const float4*>(ar + k4 * 4);
            float4 b = *reinterpret_cast<const float4*>(br + k4 * 4);
            d = fmaf(a.x, b.x, d);
            d = fmaf(a.y, b.y, d);
            d = fmaf(a.z, b.z, d);
            d = fmaf(a.w, b.w, d);
        }
        atomicMax(&slot[cl], pack64(d, (unsigned)other));
    }
    __syncthreads();

    if (tid < 16) {
        unsigned long long p = slot[tid];
        int idx = base0 + tid;
        if (rowside) {
            g_nn12[idx] = (int)(~(unsigned)p);
            out[N1 + idx] = unmono32((unsigned)(p >> 32));   // exact score
        } else {
            g_nn21[idx] = (int)(~(unsigned)p);
        }
    }
}

// Tiny mutual pass (32 blocks): both nn arrays complete after fix_kernel.
__global__ __launch_bounds__(256) void mutual_kernel(float* __restrict__ out) {
    int i = blockIdx.x * blockDim.x + threadIdx.x;
    if (i < N1) {
        int m = g_nn12[i];
        out[i] = (float)((g_nn21[m] == i) ? m : -1);   // matches0
    }
}

extern "C" void kernel_launch(void* const* d_in, const int* in_sizes, int n_in,
                              void* d_out, int out_size, void* d_ws, size_t ws_size,
                              hipStream_t stream) {
    const float* A = (const float*)d_in[0];   // desc1 [8192,128] f32
    const float* B = (const float*)d_in[1];   // desc2 [8192,128] f32
    float* out = (float*)d_out;               // [0:8192]=matches, [8192:16384]=scores

    dim3 grid(64, 64);
    simf16_kernel<<<grid, 256, 0, stream>>>(A, B);
    fix_kernel<<<1024, 256, 0, stream>>>(A, B, out);
    mutual_kernel<<<N1 / 256, 256, 0, stream>>>(out);
}

// Round 20
// 135.725 us; speedup vs baseline: 1.1867x; 1.0065x over previous
//
#include <hip/hip_runtime.h>
#include <stdint.h>

#define N1 8192
#define N2 8192
#define DK 128
#define TAU 0.08f     // repair margin (sim units); ~15 sigma of f16 dot noise
#define BIAS 256.0f   // sim in [-70,70] -> biased keys are positive floats
#define LDR 132       // staging LDS row stride in f16 (264 B)

typedef _Float16 half8 __attribute__((ext_vector_type(8)));
typedef _Float16 half4 __attribute__((ext_vector_type(4)));
typedef float floatx4 __attribute__((ext_vector_type(4)));

// Module-scope device scratch (graph-capture safe). Fully rewritten each launch.
__device__ __align__(16) _Float16 g_Af[N1 * DK];        // 2 MB
__device__ __align__(16) _Float16 g_Bf[N2 * DK];        // 2 MB
__device__ __align__(16) float2 g_rowtop2[64 * N1];     // 4 MB [128colgrp][row] tile-owned
__device__ __align__(16) float2 g_coltop2[64 * N2];     // 4 MB [128rowgrp][col]
__device__ int g_nn12[N1];
__device__ int g_nn21[N2];

// ---- biased-float keys (group top2; quant <= 3.9e-3 << TAU) ----
__device__ __forceinline__ float bkey(float v, unsigned idx) {
    unsigned b = __float_as_uint(v + BIAS);
    return __uint_as_float((b & 0xFFFFFF80u) | idx);
}
__device__ __forceinline__ float bval(float key) {
    return __uint_as_float(__float_as_uint(key) & 0xFFFFFF80u);
}
__device__ __forceinline__ int bidx(float key) {
    return (int)(__float_as_uint(key) & 127u);
}
__device__ __forceinline__ void push2f(float& t1, float& t2, float p) {
    float m = __builtin_amdgcn_fmed3f(t1, t2, p);
    t1 = fmaxf(t1, p);
    t2 = m;
}
__device__ __forceinline__ void merge2f(float& t1, float& t2, float o1, float o2) {
    float x = fmaxf(t2, o2);
    float m = __builtin_amdgcn_fmed3f(t1, o1, x);
    t1 = fmaxf(t1, o1);
    t2 = m;
}
// ---- exact monotone pack for the repair path ----
__device__ __forceinline__ unsigned mono32(float v) {
    unsigned u = __float_as_uint(v);
    return u ^ ((u & 0x80000000u) ? 0xFFFFFFFFu : 0x80000000u);
}
__device__ __forceinline__ float unmono32(unsigned k) {
    unsigned u = (k & 0x80000000u) ? (k ^ 0x80000000u) : ~k;
    return __uint_as_float(u);
}
__device__ __forceinline__ unsigned long long pack64(float d, unsigned idx) {
    return ((unsigned long long)mono32(d) << 32) | (unsigned)(~idx);
}

// fp32 -> f16 staging kernel (R19 lesson: fusing this into sim doubles staging
// bytes and blows per-XCD L2 -> sim 76->91us; the separate 6us kernel wins).
__global__ __launch_bounds__(256) void convert_kernel(const float* __restrict__ A,
                                                      const float* __restrict__ B) {
    int t = blockIdx.x * blockDim.x + threadIdx.x;
    const int perMat = N1 * (DK / 4);
    int which = (t >= perMat) ? 1 : 0;
    const float* src = which ? B : A;
    _Float16* dst = which ? g_Bf : g_Af;
    int i = which ? t - perMat : t;
    int m = i >> 5;
    int kq = i & 31;
    float4 v = *reinterpret_cast<const float4*>(src + (size_t)m * DK + kq * 4);
    half4 h = {(_Float16)v.x, (_Float16)v.y, (_Float16)v.z, (_Float16)v.w};
    *reinterpret_cast<half4*>(dst + (size_t)m * DK + kq * 4) = h;
}

// 128x128 tile per block, 4 waves, f16 LDS-staged fragments (single staging
// barrier; R17 body, 76.4us proven). Float-key shuffle top2 epilogue (R16),
// XCD swizzle. No min-waves bound (R9/R13: cap spills acc).
__global__ __launch_bounds__(256) void simf16_kernel() {
    __shared__ _Float16 As[128 * LDR];   // 33792 B
    __shared__ _Float16 Bs[128 * LDR];   // 33792 B
    __shared__ float2 lmerge[2][128];    // 2 KB

    const int tid  = threadIdx.x;
    const int lane = tid & 63;
    const int wave = tid >> 6;
    const int wm = wave >> 1, wn = wave & 1;
    const int fr = lane & 15, q = lane >> 4;

    // XCD swizzle: dispatch-neighbors share ty, clustered tx -> L2 panel reuse.
    const int flat = blockIdx.y * 64 + blockIdx.x;
    const int xcd = flat & 7;
    const int j = flat >> 3;
    const int ty = j >> 3;
    const int tx = ((j & 7) << 3) | xcd;
    const int row0 = ty * 128, col0 = tx * 128;

    // ---- stage A,B tiles (2048 16-B chunks each; fully coalesced) ----
#pragma unroll
    for (int i = 0; i < 8; ++i) {
        int f = i * 256 + tid;
        int r = f >> 4, c = f & 15;
        *reinterpret_cast<float4*>(&As[r * LDR + c * 8]) =
            *reinterpret_cast<const float4*>(g_Af + (size_t)(row0 + r) * DK + c * 8);
        *reinterpret_cast<float4*>(&Bs[r * LDR + c * 8]) =
            *reinterpret_cast<const float4*>(g_Bf + (size_t)(col0 + r) * DK + c * 8);
    }
    __syncthreads();

    floatx4 acc[4][4];
#pragma unroll
    for (int mt = 0; mt < 4; ++mt)
#pragma unroll
        for (int nt = 0; nt < 4; ++nt)
            acc[mt][nt] = (floatx4){0.f, 0.f, 0.f, 0.f};

#pragma unroll
    for (int ks = 0; ks < 4; ++ks) {
        half8 af[4], bf[4];
#pragma unroll
        for (int mt = 0; mt < 4; ++mt)
            af[mt] = *reinterpret_cast<const half8*>(&As[(wm * 64 + mt * 16 + fr) * LDR + ks * 32 + q * 8]);
#pragma unroll
        for (int nt = 0; nt < 4; ++nt)
            bf[nt] = *reinterpret_cast<const half8*>(&Bs[(wn * 64 + nt * 16 + fr) * LDR + ks * 32 + q * 8]);
#pragma unroll
        for (int mt = 0; mt < 4; ++mt)
#pragma unroll
            for (int nt = 0; nt < 4; ++nt)
                acc[mt][nt] = __builtin_amdgcn_mfma_f32_16x16x32_f16(af[mt], bf[nt], acc[mt][nt], 0, 0, 0);
    }

    // ---- row phase: top2 over 128 cols (C/D: col=lane&15, row=q*4+reg) ----
#pragma unroll
    for (int mt = 0; mt < 4; ++mt) {
#pragma unroll
        for (int reg = 0; reg < 4; ++reg) {
            float t1 = 0.f, t2 = 0.f;
#pragma unroll
            for (int nt = 0; nt < 4; ++nt)
                push2f(t1, t2, bkey(acc[mt][nt][reg], (unsigned)(wn * 64 + nt * 16 + fr)));
#pragma unroll
            for (int off = 1; off < 16; off <<= 1) {
                float o1 = __shfl_xor(t1, off, 64);
                float o2 = __shfl_xor(t2, off, 64);
                merge2f(t1, t2, o1, o2);
            }
            if (fr == 0) lmerge[wn][wm * 64 + mt * 16 + q * 4 + reg] = make_float2(t1, t2);
        }
    }
    __syncthreads();
    if (tid < 128) {
        float2 a = lmerge[0][tid], b = lmerge[1][tid];
        merge2f(a.x, a.y, b.x, b.y);
        g_rowtop2[(size_t)tx * N1 + row0 + tid] = a;   // contiguous 1 KB run
    }
    __syncthreads();

    // ---- col phase: top2 over 128 rows ----
#pragma unroll
    for (int nt = 0; nt < 4; ++nt) {
        float t1 = 0.f, t2 = 0.f;
#pragma unroll
        for (int mt = 0; mt < 4; ++mt)
#pragma unroll
            for (int reg = 0; reg < 4; ++reg)
                push2f(t1, t2, bkey(acc[mt][nt][reg], (unsigned)(wm * 64 + mt * 16 + q * 4 + reg)));
        float o1 = __shfl_xor(t1, 16, 64), o2 = __shfl_xor(t2, 16, 64);
        merge2f(t1, t2, o1, o2);
        o1 = __shfl_xor(t1, 32, 64); o2 = __shfl_xor(t2, 32, 64);
        merge2f(t1, t2, o1, o2);
        if (q == 0) lmerge[wm][wn * 64 + nt * 16 + fr] = make_float2(t1, t2);
    }
    __syncthreads();
    if (tid < 128) {
        float2 a = lmerge[0][tid], b = lmerge[1][tid];
        merge2f(a.x, a.y, b.x, b.y);
        g_coltop2[(size_t)ty * N2 + col0 + tid] = a;
    }
}

// 1024 blocks: 0..511 repair cols (g_nn21), 512..1023 repair rows (g_nn12 +
// exact scores). Independent halves run concurrently in one launch.
// Candidates within TAU of approx max get the fp32 SEQUENTIAL k-ascending
// fmaf chain (bitwise reference rounding, R6-proven).
__global__ __launch_bounds__(256) void fix_kernel(const float* __restrict__ A,
                                                  const float* __restrict__ B,
                                                  float* __restrict__ out) {
    __shared__ float2 tile[64 * 16];          // 8 KB
    __shared__ unsigned long long slot[16];
    __shared__ int cand[256];
    __shared__ int cand_cnt;

    const int tid = threadIdx.x;
    const bool rowside = blockIdx.x >= 512;
    const int base0 = (blockIdx.x & 511) * 16;
    const float2* top2 = rowside ? g_rowtop2 : g_coltop2;

#pragma unroll
    for (int i = 0; i < 4; ++i) {
        int idx = i * 256 + tid;              // 0..1023
        int grp = idx >> 4, c = idx & 15;
        tile[grp * 16 + c] = top2[(size_t)grp * N1 + base0 + c];
    }
    if (tid < 16) slot[tid] = 0ULL;
    if (tid == 0) cand_cnt = 0;
    __syncthreads();

    const int c = tid >> 4, j = tid & 15;     // 16 threads per row/col
    float mx = 0.f;                           // biased domain, all keys > 0
#pragma unroll
    for (int s = 0; s < 4; ++s)
        mx = fmaxf(mx, tile[(j * 4 + s) * 16 + c].x);
    mx = fmaxf(mx, __shfl_xor(mx, 1, 64));
    mx = fmaxf(mx, __shfl_xor(mx, 2, 64));
    mx = fmaxf(mx, __shfl_xor(mx, 4, 64));
    mx = fmaxf(mx, __shfl_xor(mx, 8, 64));
    const float thr = bval(mx) - TAU;
#pragma unroll
    for (int s = 0; s < 4; ++s) {
        int grp = j * 4 + s;
        float2 e = tile[grp * 16 + c];
        if (bval(e.x) >= thr) {
            int o = grp * 128 + bidx(e.x);
            int si = atomicAdd(&cand_cnt, 1);
            if (si < 256) cand[si] = (c << 16) | o;
        }
        if (bval(e.y) >= thr) {
            int o = grp * 128 + bidx(e.y);
            int si = atomicAdd(&cand_cnt, 1);
            if (si < 256) cand[si] = (c << 16) | o;
        }
    }
    __syncthreads();

    const int nc = min(cand_cnt, 256);
    for (int i = tid; i < nc; i += 256) {
        int pc = cand[i];
        int cl = pc >> 16, other = pc & 0xFFFF;
        const float* ar = rowside ? (A + (size_t)(base0 + cl) * DK) : (A + (size_t)other * DK);
        const float* br = rowside ? (B + (size_t)other * DK) : (B + (size_t)(base0 + cl) * DK);
        float d = 0.0f;
#pragma unroll
        for (int k4 = 0; k4 < DK / 4; ++k4) {
            float4 a = *reinterpret_cast<const float4*>(ar + k4 * 4);
            float4 b = *reinterpret_cast<const float4*>(br + k4 * 4);
            d = fmaf(a.x, b.x, d);
            d = fmaf(a.y, b.y, d);
            d = fmaf(a.z, b.z, d);
            d = fmaf(a.w, b.w, d);
        }
        atomicMax(&slot[cl], pack64(d, (unsigned)other));
    }
    __syncthreads();

    if (tid < 16) {
        unsigned long long p = slot[tid];
        int idx = base0 + tid;
        if (rowside) {
            g_nn12[idx] = (int)(~(unsigned)p);
            out[N1 + idx] = unmono32((unsigned)(p >> 32));   // exact score
        } else {
            g_nn21[idx] = (int)(~(unsigned)p);
        }
    }
}

// Tiny mutual pass (32 blocks): both nn arrays complete after fix_kernel.
__global__ __launch_bounds__(256) void mutual_kernel(float* __restrict__ out) {
    int i = blockIdx.x * blockDim.x + threadIdx.x;
    if (i < N1) {
        int m = g_nn12[i];
        out[i] = (float)((g_nn21[m] == i) ? m : -1);   // matches0
    }
}

extern "C" void kernel_launch(void* const* d_in, const int* in_sizes, int n_in,
                              void* d_out, int out_size, void* d_ws, size_t ws_size,
                              hipStream_t stream) {
    const float* A = (const float*)d_in[0];   // desc1 [8192,128] f32
    const float* B = (const float*)d_in[1];   // desc2 [8192,128] f32
    float* out = (float*)d_out;               // [0:8192]=matches, [8192:16384]=scores

    convert_kernel<<<2 * N1 * (DK / 4) / 256, 256, 0, stream>>>(A, B);
    dim3 grid(64, 64);
    simf16_kernel<<<grid, 256, 0, stream>>>();
    fix_kernel<<<1024, 256, 0, stream>>>(A, B, out);
    mutual_kernel<<<N1 / 256, 256, 0, stream>>>(out);
}

// Round 21
// 127.976 us; speedup vs baseline: 1.2586x; 1.0605x over previous
//
#include <hip/hip_runtime.h>
#include <stdint.h>

#define N1 8192
#define N2 8192
#define DK 128
#define TAU 0.08f     // repair margin (sim units); ~15 sigma of f16 dot noise
#define BIAS 256.0f   // sim in [-70,70] -> biased keys are positive floats
#define LDR 132       // B-tile LDS row stride in f16 (264 B)

typedef _Float16 half8 __attribute__((ext_vector_type(8)));
typedef _Float16 half4 __attribute__((ext_vector_type(4)));
typedef float floatx4 __attribute__((ext_vector_type(4)));

// Module-scope device scratch (graph-capture safe). Fully rewritten each launch.
__device__ __align__(16) _Float16 g_Af[N1 * DK];        // 2 MB
__device__ __align__(16) _Float16 g_Bf[N2 * DK];        // 2 MB
__device__ __align__(16) float2 g_rowtop2[64 * N1];     // 4 MB [128colgrp][row] tile-owned
__device__ __align__(16) float2 g_coltop2[64 * N2];     // 4 MB [128rowgrp][col]
__device__ int g_nn12[N1];
__device__ int g_nn21[N2];

// ---- biased-float keys (group top2; quant <= 3.9e-3 << TAU) ----
__device__ __forceinline__ float bkey(float v, unsigned idx) {
    unsigned b = __float_as_uint(v + BIAS);
    return __uint_as_float((b & 0xFFFFFF80u) | idx);
}
__device__ __forceinline__ float bval(float key) {
    return __uint_as_float(__float_as_uint(key) & 0xFFFFFF80u);
}
__device__ __forceinline__ int bidx(float key) {
    return (int)(__float_as_uint(key) & 127u);
}
__device__ __forceinline__ void push2f(float& t1, float& t2, float p) {
    float m = __builtin_amdgcn_fmed3f(t1, t2, p);
    t1 = fmaxf(t1, p);
    t2 = m;
}
__device__ __forceinline__ void merge2f(float& t1, float& t2, float o1, float o2) {
    float x = fmaxf(t2, o2);
    float m = __builtin_amdgcn_fmed3f(t1, o1, x);
    t1 = fmaxf(t1, o1);
    t2 = m;
}
// ---- exact monotone pack for the repair path ----
__device__ __forceinline__ unsigned mono32(float v) {
    unsigned u = __float_as_uint(v);
    return u ^ ((u & 0x80000000u) ? 0xFFFFFFFFu : 0x80000000u);
}
__device__ __forceinline__ float unmono32(unsigned k) {
    unsigned u = (k & 0x80000000u) ? (k ^ 0x80000000u) : ~k;
    return __uint_as_float(u);
}
__device__ __forceinline__ unsigned long long pack64(float d, unsigned idx) {
    return ((unsigned long long)mono32(d) << 32) | (unsigned)(~idx);
}

// fp32 -> f16 staging kernel (R19: fusing into sim blows per-XCD L2).
__global__ __launch_bounds__(256) void convert_kernel(const float* __restrict__ A,
                                                      const float* __restrict__ B) {
    int t = blockIdx.x * blockDim.x + threadIdx.x;
    const int perMat = N1 * (DK / 4);
    int which = (t >= perMat) ? 1 : 0;
    const float* src = which ? B : A;
    _Float16* dst = which ? g_Bf : g_Af;
    int i = which ? t - perMat : t;
    int m = i >> 5;
    int kq = i & 31;
    float4 v = *reinterpret_cast<const float4*>(src + (size_t)m * DK + kq * 4);
    half4 h = {(_Float16)v.x, (_Float16)v.y, (_Float16)v.z, (_Float16)v.w};
    *reinterpret_cast<half4*>(dst + (size_t)m * DK + kq * 4) = h;
}

// 128x128 tile per block, 4 waves. HYBRID staging (R20 theory: sim pinned at
// ~75us across all variants at 2 blocks/CU; LDS 69.6KB was the residency cap):
// B tile in LDS (33.8KB), A fragments direct from global with depth-1
// prefetch. LDS ~35.8KB -> 4 blocks/CU if VGPR<=128 (hence depth-1 not full
// prefetch). Float-key shuffle top2 epilogue (R16), XCD swizzle.
__global__ __launch_bounds__(256) void simf16_kernel() {
    __shared__ _Float16 Bs[128 * LDR];   // 33792 B
    __shared__ float2 lmerge[2][128];    // 2 KB

    const int tid  = threadIdx.x;
    const int lane = tid & 63;
    const int wave = tid >> 6;
    const int wm = wave >> 1, wn = wave & 1;
    const int fr = lane & 15, q = lane >> 4;

    // XCD swizzle: dispatch-neighbors share ty, clustered tx -> A-panel L2 reuse.
    const int flat = blockIdx.y * 64 + blockIdx.x;
    const int xcd = flat & 7;
    const int j = flat >> 3;
    const int ty = j >> 3;
    const int tx = ((j & 7) << 3) | xcd;
    const int row0 = ty * 128, col0 = tx * 128;

    // ---- stage B tile only (2048 16-B chunks; fully coalesced) ----
#pragma unroll
    for (int i = 0; i < 8; ++i) {
        int f = i * 256 + tid;
        int r = f >> 4, c = f & 15;
        *reinterpret_cast<float4*>(&Bs[r * LDR + c * 8]) =
            *reinterpret_cast<const float4*>(g_Bf + (size_t)(col0 + r) * DK + c * 8);
    }

    floatx4 acc[4][4];
#pragma unroll
    for (int mt = 0; mt < 4; ++mt)
#pragma unroll
        for (int nt = 0; nt < 4; ++nt)
            acc[mt][nt] = (floatx4){0.f, 0.f, 0.f, 0.f};

    const _Float16* Abase = g_Af + (size_t)(row0 + wm * 64 + fr) * DK + q * 8;

    // prefetch ks=0 A fragments (independent of the B staging above)
    half8 af[4], afn[4];
#pragma unroll
    for (int mt = 0; mt < 4; ++mt)
        af[mt] = *reinterpret_cast<const half8*>(Abase + mt * 16 * DK);

    __syncthreads();   // B tile ready

#pragma unroll
    for (int ks = 0; ks < 4; ++ks) {
        if (ks < 3) {
#pragma unroll
            for (int mt = 0; mt < 4; ++mt)
                afn[mt] = *reinterpret_cast<const half8*>(Abase + mt * 16 * DK + (ks + 1) * 32);
        }
        half8 bf[4];
#pragma unroll
        for (int nt = 0; nt < 4; ++nt)
            bf[nt] = *reinterpret_cast<const half8*>(&Bs[(wn * 64 + nt * 16 + fr) * LDR + ks * 32 + q * 8]);
#pragma unroll
        for (int mt = 0; mt < 4; ++mt)
#pragma unroll
            for (int nt = 0; nt < 4; ++nt)
                acc[mt][nt] = __builtin_amdgcn_mfma_f32_16x16x32_f16(af[mt], bf[nt], acc[mt][nt], 0, 0, 0);
        if (ks < 3) {
#pragma unroll
            for (int mt = 0; mt < 4; ++mt)
                af[mt] = afn[mt];
        }
    }

    // ---- row phase: top2 over 128 cols (C/D: col=lane&15, row=q*4+reg) ----
#pragma unroll
    for (int mt = 0; mt < 4; ++mt) {
#pragma unroll
        for (int reg = 0; reg < 4; ++reg) {
            float t1 = 0.f, t2 = 0.f;
#pragma unroll
            for (int nt = 0; nt < 4; ++nt)
                push2f(t1, t2, bkey(acc[mt][nt][reg], (unsigned)(wn * 64 + nt * 16 + fr)));
#pragma unroll
            for (int off = 1; off < 16; off <<= 1) {
                float o1 = __shfl_xor(t1, off, 64);
                float o2 = __shfl_xor(t2, off, 64);
                merge2f(t1, t2, o1, o2);
            }
            if (fr == 0) lmerge[wn][wm * 64 + mt * 16 + q * 4 + reg] = make_float2(t1, t2);
        }
    }
    __syncthreads();
    if (tid < 128) {
        float2 a = lmerge[0][tid], b = lmerge[1][tid];
        merge2f(a.x, a.y, b.x, b.y);
        g_rowtop2[(size_t)tx * N1 + row0 + tid] = a;   // contiguous 1 KB run
    }
    __syncthreads();

    // ---- col phase: top2 over 128 rows ----
#pragma unroll
    for (int nt = 0; nt < 4; ++nt) {
        float t1 = 0.f, t2 = 0.f;
#pragma unroll
        for (int mt = 0; mt < 4; ++mt)
#pragma unroll
            for (int reg = 0; reg < 4; ++reg)
                push2f(t1, t2, bkey(acc[mt][nt][reg], (unsigned)(wm * 64 + mt * 16 + q * 4 + reg)));
        float o1 = __shfl_xor(t1, 16, 64), o2 = __shfl_xor(t2, 16, 64);
        merge2f(t1, t2, o1, o2);
        o1 = __shfl_xor(t1, 32, 64); o2 = __shfl_xor(t2, 32, 64);
        merge2f(t1, t2, o1, o2);
        if (q == 0) lmerge[wm][wn * 64 + nt * 16 + fr] = make_float2(t1, t2);
    }
    __syncthreads();
    if (tid < 128) {
        float2 a = lmerge[0][tid], b = lmerge[1][tid];
        merge2f(a.x, a.y, b.x, b.y);
        g_coltop2[(size_t)ty * N2 + col0 + tid] = a;
    }
}

// 1024 blocks: 0..511 repair cols (g_nn21), 512..1023 repair rows (g_nn12 +
// exact scores). Candidates within TAU of approx max get the fp32 SEQUENTIAL
// k-ascending fmaf chain (bitwise reference rounding, R6-proven).
__global__ __launch_bounds__(256) void fix_kernel(const float* __restrict__ A,
                                                  const float* __restrict__ B,
                                                  float* __restrict__ out) {
    __shared__ float2 tile[64 * 16];          // 8 KB
    __shared__ unsigned long long slot[16];
    __shared__ int cand[256];
    __shared__ int cand_cnt;

    const int tid = threadIdx.x;
    const bool rowside = blockIdx.x >= 512;
    const int base0 = (blockIdx.x & 511) * 16;
    const float2* top2 = rowside ? g_rowtop2 : g_coltop2;

#pragma unroll
    for (int i = 0; i < 4; ++i) {
        int idx = i * 256 + tid;              // 0..1023
        int grp = idx >> 4, c = idx & 15;
        tile[grp * 16 + c] = top2[(size_t)grp * N1 + base0 + c];
    }
    if (tid < 16) slot[tid] = 0ULL;
    if (tid == 0) cand_cnt = 0;
    __syncthreads();

    const int c = tid >> 4, j = tid & 15;     // 16 threads per row/col
    float mx = 0.f;                           // biased domain, all keys > 0
#pragma unroll
    for (int s = 0; s < 4; ++s)
        mx = fmaxf(mx, tile[(j * 4 + s) * 16 + c].x);
    mx = fmaxf(mx, __shfl_xor(mx, 1, 64));
    mx = fmaxf(mx, __shfl_xor(mx, 2, 64));
    mx = fmaxf(mx, __shfl_xor(mx, 4, 64));
    mx = fmaxf(mx, __shfl_xor(mx, 8, 64));
    const float thr = bval(mx) - TAU;
#pragma unroll
    for (int s = 0; s < 4; ++s) {
        int grp = j * 4 + s;
        float2 e = tile[grp * 16 + c];
        if (bval(e.x) >= thr) {
            int o = grp * 128 + bidx(e.x);
            int si = atomicAdd(&cand_cnt, 1);
            if (si < 256) cand[si] = (c << 16) | o;
        }
        if (bval(e.y) >= thr) {
            int o = grp * 128 + bidx(e.y);
            int si = atomicAdd(&cand_cnt, 1);
            if (si < 256) cand[si] = (c << 16) | o;
        }
    }
    __syncthreads();

    const int nc = min(cand_cnt, 256);
    for (int i = tid; i < nc; i += 256) {
        int pc = cand[i];
        int cl = pc >> 16, other = pc & 0xFFFF;
        const float* ar = rowside ? (A + (size_t)(base0 + cl) * DK) : (A + (size_t)other * DK);
        const float* br = rowside ? (B + (size_t)other * DK) : (B + (size_t)(base0 + cl) * DK);
        float d = 0.0f;
#pragma unroll
        for (int k4 = 0; k4 < DK / 4; ++k4) {
            float4 a = *reinterpret_cast<const float4*>(ar + k4 * 4);
            float4 b = *reinterpret_cast<const float4*>(br + k4 * 4);
            d = fmaf(a.x, b.x, d);
            d = fmaf(a.y, b.y, d);
            d = fmaf(a.z, b.z, d);
            d = fmaf(a.w, b.w, d);
        }
        atomicMax(&slot[cl], pack64(d, (unsigned)other));
    }
    __syncthreads();

    if (tid < 16) {
        unsigned long long p = slot[tid];
        int idx = base0 + tid;
        if (rowside) {
            g_nn12[idx] = (int)(~(unsigned)p);
            out[N1 + idx] = unmono32((unsigned)(p >> 32));   // exact score
        } else {
            g_nn21[idx] = (int)(~(unsigned)p);
        }
    }
}

// Tiny mutual pass (32 blocks): both nn arrays complete after fix_kernel.
__global__ __launch_bounds__(256) void mutual_kernel(float* __restrict__ out) {
    int i = blockIdx.x * blockDim.x + threadIdx.x;
    if (i < N1) {
        int m = g_nn12[i];
        out[i] = (float)((g_nn21[m] == i) ? m : -1);   // matches0
    }
}

extern "C" void kernel_launch(void* const* d_in, const int* in_sizes, int n_in,
                              void* d_out, int out_size, void* d_ws, size_t ws_size,
                              hipStream_t stream) {
    const float* A = (const float*)d_in[0];   // desc1 [8192,128] f32
    const float* B = (const float*)d_in[1];   // desc2 [8192,128] f32
    float* out = (float*)d_out;               // [0:8192]=matches, [8192:16384]=scores

    convert_kernel<<<2 * N1 * (DK / 4) / 256, 256, 0, stream>>>(A, B);
    dim3 grid(64, 64);
    simf16_kernel<<<grid, 256, 0, stream>>>();
    fix_kernel<<<1024, 256, 0, stream>>>(A, B, out);
    mutual_kernel<<<N1 / 256, 256, 0, stream>>>(out);
}